// Round 22
// baseline (136.651 us; speedup 1.0000x reference)
//
#include <hip/hip_runtime.h>

// BeamDelay2AntFreq: (256,32,8,4,2,48) complex -> ifft4(V) -> ifft8(H) -> fft48(t),
// fftshifts folded into (-1)^{h+v+f}; ortho norm 1/sqrt(1536).
// OUTPUT: interleaved bf16 pairs IMAG FIRST: dword = im | (re<<16), (b,c,row,f) order.
// R22 = R19 + transposed S layout: phase A writes S[j][b] at T[r*RP+4j+b] so
// phase B reads each j's four b-slices as ONE aligned float4 (96 -> 24 LDS
// read wave-insts per wave). RP=52 for 16B alignment; still 6 blocks/CU.

namespace {

constexpr int RP = 52;       // T/S row stride (floats); 16B-aligned rows, span 48 < 52
constexpr float NORM = 0.02551551815399144f;  // 1/sqrt(1536)
constexpr float R2  = 0.70710678f;            // 1/sqrt(2)
constexpr float C30 = 0.86602540f;            // cos(30)

constexpr float COS48[48] = {
  1.0f,        0.99144486f,  0.96592583f,  0.92387953f,  0.86602540f,  0.79335334f,
  0.70710678f, 0.60876143f,  0.5f,         0.38268343f,  0.25881905f,  0.13052619f,
  0.0f,       -0.13052619f, -0.25881905f, -0.38268343f, -0.5f,        -0.60876143f,
 -0.70710678f,-0.79335334f, -0.86602540f, -0.92387953f, -0.96592583f, -0.99144486f,
 -1.0f,       -0.99144486f, -0.96592583f, -0.92387953f, -0.86602540f, -0.79335334f,
 -0.70710678f,-0.60876143f, -0.5f,        -0.38268343f, -0.25881905f, -0.13052619f,
  0.0f,        0.13052619f,  0.25881905f,  0.38268343f,  0.5f,         0.60876143f,
  0.70710678f, 0.79335334f,  0.86602540f,  0.92387953f,  0.96592583f,  0.99144486f
};
constexpr float SIN48[48] = {
  0.0f,        0.13052619f,  0.25881905f,  0.38268343f,  0.5f,         0.60876143f,
  0.70710678f, 0.79335334f,  0.86602540f,  0.92387953f,  0.96592583f,  0.99144486f,
  1.0f,        0.99144486f,  0.96592583f,  0.92387953f,  0.86602540f,  0.79335334f,
  0.70710678f, 0.60876143f,  0.5f,         0.38268343f,  0.25881905f,  0.13052619f,
  0.0f,       -0.13052619f, -0.25881905f, -0.38268343f, -0.5f,        -0.60876143f,
 -0.70710678f,-0.79335334f, -0.86602540f, -0.92387953f, -0.96592583f, -0.99144486f,
 -1.0f,       -0.99144486f, -0.96592583f, -0.92387953f, -0.86602540f, -0.79335334f,
 -0.70710678f,-0.60876143f, -0.5f,        -0.38268343f, -0.25881905f, -0.13052619f
};

__device__ __forceinline__ unsigned bf16_rne(float x) {
  unsigned u = __float_as_uint(x);
  u += 0x7FFFu + ((u >> 16) & 1u);
  return u >> 16;
}

__global__ __launch_bounds__(256, 6)
void bd2af_kernel(const float* __restrict__ xr, const float* __restrict__ xi,
                  unsigned* __restrict__ out, int nbc) {
  __shared__ __align__(16) float Tr[64 * RP], Ti[64 * RP];   // X->T1->Y->S overlay

  const int tid = threadIdx.x;
  const int bc = blockIdx.x;
  if (bc >= nbc) return;

  const float* gxr = xr + (size_t)bc * 3072;
  const float* gxi = xi + (size_t)bc * 3072;

  // ---- V phase: global -> reg, 4-pt inverse FFT (kernel i^{V v'}), write T1 ----
  {
    const int hq = tid >> 5;           // 0..7
    const int p  = (tid >> 4) & 1;
    const int tc = tid & 15;
    const int t0 = 3 * tc;
    const int rowb = hq * 8 + p;       // row = rowb + 2V
#pragma unroll
    for (int k = 0; k < 3; ++k) {
      const int tt = t0 + k;
      const float x0r = gxr[(rowb + 0) * 48 + tt], x0i = gxi[(rowb + 0) * 48 + tt];
      const float x1r = gxr[(rowb + 2) * 48 + tt], x1i = gxi[(rowb + 2) * 48 + tt];
      const float x2r = gxr[(rowb + 4) * 48 + tt], x2i = gxi[(rowb + 4) * 48 + tt];
      const float x3r = gxr[(rowb + 6) * 48 + tt], x3i = gxi[(rowb + 6) * 48 + tt];
      const float e0r = x0r + x2r, e0i = x0i + x2i;
      const float e1r = x0r - x2r, e1i = x0i - x2i;
      const float o0r = x1r + x3r, o0i = x1i + x3i;
      const float o1r = x1r - x3r, o1i = x1i - x3i;
      Tr[(rowb + 0) * RP + tt] = e0r + o0r;  Ti[(rowb + 0) * RP + tt] = e0i + o0i;
      Tr[(rowb + 2) * RP + tt] = e1r - o1i;  Ti[(rowb + 2) * RP + tt] = e1i + o1r;  // +i*o1
      Tr[(rowb + 4) * RP + tt] = e0r - o0r;  Ti[(rowb + 4) * RP + tt] = e0i - o0i;
      Tr[(rowb + 6) * RP + tt] = e1r + o1i;  Ti[(rowb + 6) * RP + tt] = e1i - o1r;  // -i*o1
    }
  }
  __syncthreads();

  // ---- H phase (128 threads): 8-pt inverse FFT in-place, with (-1)^{h'+v'} ----
  if (tid < 128) {
    const int vq = tid >> 5;           // 0..3
    const int p  = (tid >> 4) & 1;
    const int tc = tid & 15;
    const int t0 = 3 * tc;
    const int rowb = 2 * vq + p;       // row = rowb + 8H
    const float sgnE = (vq & 1) ? -1.f : 1.f;   // (-1)^{h'+vq}, h' even
    const float sgnO = -sgnE;                   // h' odd
#pragma unroll
    for (int k = 0; k < 3; ++k) {
      const int tt = t0 + k;
      const float t0r = Tr[(rowb +  0) * RP + tt], t0i = Ti[(rowb +  0) * RP + tt];
      const float t1r = Tr[(rowb +  8) * RP + tt], t1i = Ti[(rowb +  8) * RP + tt];
      const float t2r = Tr[(rowb + 16) * RP + tt], t2i = Ti[(rowb + 16) * RP + tt];
      const float t3r = Tr[(rowb + 24) * RP + tt], t3i = Ti[(rowb + 24) * RP + tt];
      const float t4r = Tr[(rowb + 32) * RP + tt], t4i = Ti[(rowb + 32) * RP + tt];
      const float t5r = Tr[(rowb + 40) * RP + tt], t5i = Ti[(rowb + 40) * RP + tt];
      const float t6r = Tr[(rowb + 48) * RP + tt], t6i = Ti[(rowb + 48) * RP + tt];
      const float t7r = Tr[(rowb + 56) * RP + tt], t7i = Ti[(rowb + 56) * RP + tt];
      const float e0r = t0r + t4r, e0i = t0i + t4i, e1r = t0r - t4r, e1i = t0i - t4i;
      const float o0r = t2r + t6r, o0i = t2i + t6i, o1r = t2r - t6r, o1i = t2i - t6i;
      const float E0r = e0r + o0r, E0i = e0i + o0i;
      const float E2r = e0r - o0r, E2i = e0i - o0i;
      const float E1r = e1r - o1i, E1i = e1i + o1r;   // e1 + i o1
      const float E3r = e1r + o1i, E3i = e1i - o1r;   // e1 - i o1
      const float f0r = t1r + t5r, f0i = t1i + t5i, f1r = t1r - t5r, f1i = t1i - t5i;
      const float g0r = t3r + t7r, g0i = t3i + t7i, g1r = t3r - t7r, g1i = t3i - t7i;
      const float O0r = f0r + g0r, O0i = f0i + g0i;
      const float O2r = f0r - g0r, O2i = f0i - g0i;
      const float O1r = f1r - g1i, O1i = f1i + g1r;
      const float O3r = f1r + g1i, O3i = f1i - g1r;
      const float W1r = R2 * (O1r - O1i), W1i = R2 * (O1r + O1i);
      const float W3r = R2 * (-O3r - O3i), W3i = R2 * (O3r - O3i);
      Tr[(rowb +  0) * RP + tt] = sgnE * (E0r + O0r);  Ti[(rowb +  0) * RP + tt] = sgnE * (E0i + O0i);
      Tr[(rowb + 32) * RP + tt] = sgnE * (E0r - O0r);  Ti[(rowb + 32) * RP + tt] = sgnE * (E0i - O0i);
      Tr[(rowb + 16) * RP + tt] = sgnE * (E2r - O2i);  Ti[(rowb + 16) * RP + tt] = sgnE * (E2i + O2r);
      Tr[(rowb + 48) * RP + tt] = sgnE * (E2r + O2i);  Ti[(rowb + 48) * RP + tt] = sgnE * (E2i - O2r);
      Tr[(rowb +  8) * RP + tt] = sgnO * (E1r + W1r);  Ti[(rowb +  8) * RP + tt] = sgnO * (E1i + W1i);
      Tr[(rowb + 40) * RP + tt] = sgnO * (E1r - W1r);  Ti[(rowb + 40) * RP + tt] = sgnO * (E1i - W1i);
      Tr[(rowb + 24) * RP + tt] = sgnO * (E3r + W3r);  Ti[(rowb + 24) * RP + tt] = sgnO * (E3i + W3i);
      Tr[(rowb + 56) * RP + tt] = sgnO * (E3r - W3r);  Ti[(rowb + 56) * RP + tt] = sgnO * (E3i - W3i);
    }
  }
  __syncthreads();

  // ---- Phase A: radix-12 DFT per (row, b); S stored TRANSPOSED: T[r*RP+4j+b] ----
  // Rows wave-private (r = tid>>2): all lane reads of row r precede writes
  // (program order, may-alias LDS) -> safe overlay; phase B same-wave -> no barrier.
  {
    const int r = tid >> 2;
    const int b = tid & 3;
    float zr[12], zi[12];
#pragma unroll
    for (int a = 0; a < 12; ++a) {
      zr[a] = Tr[r * RP + 4 * a + b];
      zi[a] = Ti[r * RP + 4 * a + b];
    }
    float h0r[3], h0i[3], h1r[3], h1i[3], h2r[3], h2i[3], h3r[3], h3i[3];
#pragma unroll
    for (int a2 = 0; a2 < 3; ++a2) {
      const float e0r = zr[a2] + zr[a2 + 6], e0i = zi[a2] + zi[a2 + 6];
      const float e1r = zr[a2] - zr[a2 + 6], e1i = zi[a2] - zi[a2 + 6];
      const float o0r = zr[a2 + 3] + zr[a2 + 9], o0i = zi[a2 + 3] + zi[a2 + 9];
      const float o1r = zr[a2 + 3] - zr[a2 + 9], o1i = zi[a2 + 3] - zi[a2 + 9];
      h0r[a2] = e0r + o0r;  h0i[a2] = e0i + o0i;
      h2r[a2] = e0r - o0r;  h2i[a2] = e0i - o0i;
      h1r[a2] = e1r + o1i;  h1i[a2] = e1i - o1r;   // e1 - i o1 (forward)
      h3r[a2] = e1r - o1i;  h3i[a2] = e1i + o1r;   // e1 + i o1
    }
    {
      float a, bb;
      a = h1r[1]; bb = h1i[1];
      h1r[1] = C30 * a + 0.5f * bb;  h1i[1] = C30 * bb - 0.5f * a;
      a = h2r[1]; bb = h2i[1];
      h2r[1] = 0.5f * a + C30 * bb;  h2i[1] = 0.5f * bb - C30 * a;
      a = h3r[1]; bb = h3i[1];
      h3r[1] = bb;                   h3i[1] = -a;
      a = h1r[2]; bb = h1i[2];
      h1r[2] = 0.5f * a + C30 * bb;  h1i[2] = 0.5f * bb - C30 * a;
      a = h2r[2]; bb = h2i[2];
      h2r[2] = -0.5f * a + C30 * bb; h2i[2] = -0.5f * bb - C30 * a;
      h3r[2] = -h3r[2];              h3i[2] = -h3i[2];
    }
    float s_r[12], s_i[12];
#define DFT3(J1, HR, HI)                                                    \
    {                                                                       \
      const float tr_ = HR[1] + HR[2], ti_ = HI[1] + HI[2];                 \
      const float dr_ = HR[1] - HR[2], di_ = HI[1] - HI[2];                 \
      const float mr_ = HR[0] - 0.5f * tr_, mi_ = HI[0] - 0.5f * ti_;       \
      const float wr_ = C30 * dr_, wi_ = C30 * di_;                         \
      s_r[J1]     = HR[0] + tr_;  s_i[J1]     = HI[0] + ti_;                \
      s_r[J1 + 4] = mr_ + wi_;    s_i[J1 + 4] = mi_ - wr_;                  \
      s_r[J1 + 8] = mr_ - wi_;    s_i[J1 + 8] = mi_ + wr_;                  \
    }
    DFT3(0, h0r, h0i)
    DFT3(1, h1r, h1i)
    DFT3(2, h2r, h2i)
    DFT3(3, h3r, h3i)
#undef DFT3
#pragma unroll
    for (int j = 0; j < 12; ++j) {
      Tr[r * RP + 4 * j + b] = s_r[j];   // transposed: S[j][b]
      Ti[r * RP + 4 * j + b] = s_i[j];
    }
  }
  // NO barrier: phase B reads S rows written by the same wave.

  // ---- Phase B: float4 S reads, W48 twiddle combine, pack, direct store ----
  {
    const int r = tid >> 2;
    const int c = tid & 3;
    const float a1r = (c == 0) ? 1.f : ((c == 2) ? -1.f : 0.f);
    const float a1i = (c == 1) ? -1.f : ((c == 3) ? 1.f : 0.f);
    const float s2  = (c & 1) ? -1.f : 1.f;
    unsigned pk[12];
#pragma unroll
    for (int j = 0; j < 12; ++j) {
      const float4 S4r = *reinterpret_cast<const float4*>(&Tr[r * RP + 4 * j]);
      const float4 S4i = *reinterpret_cast<const float4*>(&Ti[r * RP + 4 * j]);
      float orr = S4r.x, oii = S4i.x;            // b' = 0
      {  // b' = 1: (-i)^c * S1 * W48^j
        const float wr = COS48[j], wi = -SIN48[j];
        const float tr = S4r.y * wr - S4i.y * wi, ti = S4r.y * wi + S4i.y * wr;
        orr += a1r * tr - a1i * ti;
        oii += a1r * ti + a1i * tr;
      }
      {  // b' = 2: (-1)^c * S2 * W48^{2j}
        const float wr = COS48[(2 * j) % 48], wi = -SIN48[(2 * j) % 48];
        const float tr = S4r.z * wr - S4i.z * wi, ti = S4r.z * wi + S4i.z * wr;
        orr += s2 * tr;
        oii += s2 * ti;
      }
      {  // b' = 3: (i)^c * S3 * W48^{3j}
        const float wr = COS48[(3 * j) % 48], wi = -SIN48[(3 * j) % 48];
        const float tr = S4r.w * wr - S4i.w * wi, ti = S4r.w * wi + S4i.w * wr;
        orr += a1r * tr + a1i * ti;
        oii += a1r * ti - a1i * tr;
      }
      const float s = (j & 1) ? -NORM : NORM;   // (-1)^f = (-1)^j since f = 12c+j
      pk[j] = bf16_rne(oii * s) | (bf16_rne(orr * s) << 16);
    }
    unsigned* og = out + (size_t)bc * 3072 + r * 48 + c * 12;
    *reinterpret_cast<uint4*>(og)     = make_uint4(pk[0], pk[1], pk[2],  pk[3]);
    *reinterpret_cast<uint4*>(og + 4) = make_uint4(pk[4], pk[5], pk[6],  pk[7]);
    *reinterpret_cast<uint4*>(og + 8) = make_uint4(pk[8], pk[9], pk[10], pk[11]);
  }
}

} // namespace

extern "C" void kernel_launch(void* const* d_in, const int* in_sizes, int n_in,
                              void* d_out, int out_size, void* d_ws, size_t ws_size,
                              hipStream_t stream) {
  const float* xr = (const float*)d_in[0];   // dict order: x_real first
  const float* xi = (const float*)d_in[1];
  unsigned* out = (unsigned*)d_out;          // dword = im(bf16) | re(bf16)<<16
  const int nbc = in_sizes[0] / 3072;        // 8192 blocks of (8*4*2*48)
  bd2af_kernel<<<nbc, 256, 0, stream>>>(xr, xi, out, nbc);
}

// Round 23
// 64.515 us; speedup vs baseline: 2.1181x; 2.1181x over previous
//
#include <hip/hip_runtime.h>

// BeamDelay2AntFreq: (256,32,8,4,2,48) complex -> ifft4(V) -> ifft8(H) -> fft48(t),
// fftshifts folded into (-1)^{h+v+f}; ortho norm 1/sqrt(1536).
// OUTPUT: interleaved bf16 pairs IMAG FIRST: dword = im | (re<<16), (b,c,row,f) order.
// R23 = R19 with phase B re-split by j: thread (r,jq) computes ALL 4 c-outputs
// for its 3 j's via a 4-pt DFT over b (kernel (-i)^{bc}). B's LDS reads drop
// 96 -> 24 floats/thread; twiddle products once per (b,j). All-scalar (no
// arrays/DPP/float4 in B) to avoid the R21/R22 scratch trigger.

namespace {

constexpr int RP = 49;       // T/S row stride (floats); span 48 < 49 => rows wave-private
constexpr float NORM = 0.02551551815399144f;  // 1/sqrt(1536)
constexpr float R2  = 0.70710678f;            // 1/sqrt(2)
constexpr float C30 = 0.86602540f;            // cos(30)

constexpr float COS48[48] = {
  1.0f,        0.99144486f,  0.96592583f,  0.92387953f,  0.86602540f,  0.79335334f,
  0.70710678f, 0.60876143f,  0.5f,         0.38268343f,  0.25881905f,  0.13052619f,
  0.0f,       -0.13052619f, -0.25881905f, -0.38268343f, -0.5f,        -0.60876143f,
 -0.70710678f,-0.79335334f, -0.86602540f, -0.92387953f, -0.96592583f, -0.99144486f,
 -1.0f,       -0.99144486f, -0.96592583f, -0.92387953f, -0.86602540f, -0.79335334f,
 -0.70710678f,-0.60876143f, -0.5f,        -0.38268343f, -0.25881905f, -0.13052619f,
  0.0f,        0.13052619f,  0.25881905f,  0.38268343f,  0.5f,         0.60876143f,
  0.70710678f, 0.79335334f,  0.86602540f,  0.92387953f,  0.96592583f,  0.99144486f
};
constexpr float SIN48[48] = {
  0.0f,        0.13052619f,  0.25881905f,  0.38268343f,  0.5f,         0.60876143f,
  0.70710678f, 0.79335334f,  0.86602540f,  0.92387953f,  0.96592583f,  0.99144486f,
  1.0f,        0.99144486f,  0.96592583f,  0.92387953f,  0.86602540f,  0.79335334f,
  0.70710678f, 0.60876143f,  0.5f,         0.38268343f,  0.25881905f,  0.13052619f,
  0.0f,       -0.13052619f, -0.25881905f, -0.38268343f, -0.5f,        -0.60876143f,
 -0.70710678f,-0.79335334f, -0.86602540f, -0.92387953f, -0.96592583f, -0.99144486f,
 -1.0f,       -0.99144486f, -0.96592583f, -0.92387953f, -0.86602540f, -0.79335334f,
 -0.70710678f,-0.60876143f, -0.5f,        -0.38268343f, -0.25881905f, -0.13052619f
};

__device__ __forceinline__ unsigned bf16_rne(float x) {
  unsigned u = __float_as_uint(x);
  u += 0x7FFFu + ((u >> 16) & 1u);
  return u >> 16;
}

__global__ __launch_bounds__(256, 6)
void bd2af_kernel(const float* __restrict__ xr, const float* __restrict__ xi,
                  unsigned* __restrict__ out, int nbc) {
  __shared__ float Tr[64 * RP], Ti[64 * RP];   // X->T1->Y->S overlay

  const int tid = threadIdx.x;
  const int bc = blockIdx.x;
  if (bc >= nbc) return;

  const float* gxr = xr + (size_t)bc * 3072;
  const float* gxi = xi + (size_t)bc * 3072;

  // ---- V phase: global -> reg, 4-pt inverse FFT (kernel i^{V v'}), write T1 ----
  {
    const int hq = tid >> 5;           // 0..7
    const int p  = (tid >> 4) & 1;
    const int tc = tid & 15;
    const int t0 = 3 * tc;
    const int rowb = hq * 8 + p;       // row = rowb + 2V
#pragma unroll
    for (int k = 0; k < 3; ++k) {
      const int tt = t0 + k;
      const float x0r = gxr[(rowb + 0) * 48 + tt], x0i = gxi[(rowb + 0) * 48 + tt];
      const float x1r = gxr[(rowb + 2) * 48 + tt], x1i = gxi[(rowb + 2) * 48 + tt];
      const float x2r = gxr[(rowb + 4) * 48 + tt], x2i = gxi[(rowb + 4) * 48 + tt];
      const float x3r = gxr[(rowb + 6) * 48 + tt], x3i = gxi[(rowb + 6) * 48 + tt];
      const float e0r = x0r + x2r, e0i = x0i + x2i;
      const float e1r = x0r - x2r, e1i = x0i - x2i;
      const float o0r = x1r + x3r, o0i = x1i + x3i;
      const float o1r = x1r - x3r, o1i = x1i - x3i;
      Tr[(rowb + 0) * RP + tt] = e0r + o0r;  Ti[(rowb + 0) * RP + tt] = e0i + o0i;
      Tr[(rowb + 2) * RP + tt] = e1r - o1i;  Ti[(rowb + 2) * RP + tt] = e1i + o1r;  // +i*o1
      Tr[(rowb + 4) * RP + tt] = e0r - o0r;  Ti[(rowb + 4) * RP + tt] = e0i - o0i;
      Tr[(rowb + 6) * RP + tt] = e1r + o1i;  Ti[(rowb + 6) * RP + tt] = e1i - o1r;  // -i*o1
    }
  }
  __syncthreads();

  // ---- H phase (128 threads): 8-pt inverse FFT in-place, with (-1)^{h'+v'} ----
  if (tid < 128) {
    const int vq = tid >> 5;           // 0..3
    const int p  = (tid >> 4) & 1;
    const int tc = tid & 15;
    const int t0 = 3 * tc;
    const int rowb = 2 * vq + p;       // row = rowb + 8H
    const float sgnE = (vq & 1) ? -1.f : 1.f;   // (-1)^{h'+vq}, h' even
    const float sgnO = -sgnE;                   // h' odd
#pragma unroll
    for (int k = 0; k < 3; ++k) {
      const int tt = t0 + k;
      const float t0r = Tr[(rowb +  0) * RP + tt], t0i = Ti[(rowb +  0) * RP + tt];
      const float t1r = Tr[(rowb +  8) * RP + tt], t1i = Ti[(rowb +  8) * RP + tt];
      const float t2r = Tr[(rowb + 16) * RP + tt], t2i = Ti[(rowb + 16) * RP + tt];
      const float t3r = Tr[(rowb + 24) * RP + tt], t3i = Ti[(rowb + 24) * RP + tt];
      const float t4r = Tr[(rowb + 32) * RP + tt], t4i = Ti[(rowb + 32) * RP + tt];
      const float t5r = Tr[(rowb + 40) * RP + tt], t5i = Ti[(rowb + 40) * RP + tt];
      const float t6r = Tr[(rowb + 48) * RP + tt], t6i = Ti[(rowb + 48) * RP + tt];
      const float t7r = Tr[(rowb + 56) * RP + tt], t7i = Ti[(rowb + 56) * RP + tt];
      const float e0r = t0r + t4r, e0i = t0i + t4i, e1r = t0r - t4r, e1i = t0i - t4i;
      const float o0r = t2r + t6r, o0i = t2i + t6i, o1r = t2r - t6r, o1i = t2i - t6i;
      const float E0r = e0r + o0r, E0i = e0i + o0i;
      const float E2r = e0r - o0r, E2i = e0i - o0i;
      const float E1r = e1r - o1i, E1i = e1i + o1r;   // e1 + i o1
      const float E3r = e1r + o1i, E3i = e1i - o1r;   // e1 - i o1
      const float f0r = t1r + t5r, f0i = t1i + t5i, f1r = t1r - t5r, f1i = t1i - t5i;
      const float g0r = t3r + t7r, g0i = t3i + t7i, g1r = t3r - t7r, g1i = t3i - t7i;
      const float O0r = f0r + g0r, O0i = f0i + g0i;
      const float O2r = f0r - g0r, O2i = f0i - g0i;
      const float O1r = f1r - g1i, O1i = f1i + g1r;
      const float O3r = f1r + g1i, O3i = f1i - g1r;
      const float W1r = R2 * (O1r - O1i), W1i = R2 * (O1r + O1i);
      const float W3r = R2 * (-O3r - O3i), W3i = R2 * (O3r - O3i);
      Tr[(rowb +  0) * RP + tt] = sgnE * (E0r + O0r);  Ti[(rowb +  0) * RP + tt] = sgnE * (E0i + O0i);
      Tr[(rowb + 32) * RP + tt] = sgnE * (E0r - O0r);  Ti[(rowb + 32) * RP + tt] = sgnE * (E0i - O0i);
      Tr[(rowb + 16) * RP + tt] = sgnE * (E2r - O2i);  Ti[(rowb + 16) * RP + tt] = sgnE * (E2i + O2r);
      Tr[(rowb + 48) * RP + tt] = sgnE * (E2r + O2i);  Ti[(rowb + 48) * RP + tt] = sgnE * (E2i - O2r);
      Tr[(rowb +  8) * RP + tt] = sgnO * (E1r + W1r);  Ti[(rowb +  8) * RP + tt] = sgnO * (E1i + W1i);
      Tr[(rowb + 40) * RP + tt] = sgnO * (E1r - W1r);  Ti[(rowb + 40) * RP + tt] = sgnO * (E1i - W1i);
      Tr[(rowb + 24) * RP + tt] = sgnO * (E3r + W3r);  Ti[(rowb + 24) * RP + tt] = sgnO * (E3i + W3i);
      Tr[(rowb + 56) * RP + tt] = sgnO * (E3r - W3r);  Ti[(rowb + 56) * RP + tt] = sgnO * (E3i - W3i);
    }
  }
  __syncthreads();

  // ---- Phase A: radix-12 DFT per (row, b); S[b][j] at T[r*RP + b*12 + j] ----
  // (identical to R19 — compiles clean, rows wave-private, overlay safe)
  {
    const int r = tid >> 2;
    const int b = tid & 3;
    float zr[12], zi[12];
#pragma unroll
    for (int a = 0; a < 12; ++a) {
      zr[a] = Tr[r * RP + 4 * a + b];
      zi[a] = Ti[r * RP + 4 * a + b];
    }
    float h0r[3], h0i[3], h1r[3], h1i[3], h2r[3], h2i[3], h3r[3], h3i[3];
#pragma unroll
    for (int a2 = 0; a2 < 3; ++a2) {
      const float e0r = zr[a2] + zr[a2 + 6], e0i = zi[a2] + zi[a2 + 6];
      const float e1r = zr[a2] - zr[a2 + 6], e1i = zi[a2] - zi[a2 + 6];
      const float o0r = zr[a2 + 3] + zr[a2 + 9], o0i = zi[a2 + 3] + zi[a2 + 9];
      const float o1r = zr[a2 + 3] - zr[a2 + 9], o1i = zi[a2 + 3] - zi[a2 + 9];
      h0r[a2] = e0r + o0r;  h0i[a2] = e0i + o0i;
      h2r[a2] = e0r - o0r;  h2i[a2] = e0i - o0i;
      h1r[a2] = e1r + o1i;  h1i[a2] = e1i - o1r;   // e1 - i o1 (forward)
      h3r[a2] = e1r - o1i;  h3i[a2] = e1i + o1r;   // e1 + i o1
    }
    {
      float a, bb;
      a = h1r[1]; bb = h1i[1];
      h1r[1] = C30 * a + 0.5f * bb;  h1i[1] = C30 * bb - 0.5f * a;
      a = h2r[1]; bb = h2i[1];
      h2r[1] = 0.5f * a + C30 * bb;  h2i[1] = 0.5f * bb - C30 * a;
      a = h3r[1]; bb = h3i[1];
      h3r[1] = bb;                   h3i[1] = -a;
      a = h1r[2]; bb = h1i[2];
      h1r[2] = 0.5f * a + C30 * bb;  h1i[2] = 0.5f * bb - C30 * a;
      a = h2r[2]; bb = h2i[2];
      h2r[2] = -0.5f * a + C30 * bb; h2i[2] = -0.5f * bb - C30 * a;
      h3r[2] = -h3r[2];              h3i[2] = -h3i[2];
    }
    float s_r[12], s_i[12];
#define DFT3(J1, HR, HI)                                                    \
    {                                                                       \
      const float tr_ = HR[1] + HR[2], ti_ = HI[1] + HI[2];                 \
      const float dr_ = HR[1] - HR[2], di_ = HI[1] - HI[2];                 \
      const float mr_ = HR[0] - 0.5f * tr_, mi_ = HI[0] - 0.5f * ti_;       \
      const float wr_ = C30 * dr_, wi_ = C30 * di_;                         \
      s_r[J1]     = HR[0] + tr_;  s_i[J1]     = HI[0] + ti_;                \
      s_r[J1 + 4] = mr_ + wi_;    s_i[J1 + 4] = mi_ - wr_;                  \
      s_r[J1 + 8] = mr_ - wi_;    s_i[J1 + 8] = mi_ + wr_;                  \
    }
    DFT3(0, h0r, h0i)
    DFT3(1, h1r, h1i)
    DFT3(2, h2r, h2i)
    DFT3(3, h3r, h3i)
#undef DFT3
#pragma unroll
    for (int j = 0; j < 12; ++j) {
      Tr[r * RP + b * 12 + j] = s_r[j];
      Ti[r * RP + b * 12 + j] = s_i[j];
    }
  }
  // NO barrier: phase B reads S rows written by the same wave.

  // ---- Phase B (j-split): thread (r, jq) -> j in {3jq..3jq+2}, all 4 c ----
  // out[12c+j] = sum_b (-i)^{bc} * T_b,  T_b = S[b][j] * W48^{bj}  (4-pt DFT over b)
  {
    const int r = tid >> 2;
    const int jq = tid & 3;
    unsigned* og = out + (size_t)bc * 3072 + r * 48;
#pragma unroll
    for (int k = 0; k < 3; ++k) {
      const int j = 3 * jq + k;
      const float S0r = Tr[r * RP + j],      S0i = Ti[r * RP + j];
      const float S1r = Tr[r * RP + 12 + j], S1i = Ti[r * RP + 12 + j];
      const float S2r = Tr[r * RP + 24 + j], S2i = Ti[r * RP + 24 + j];
      const float S3r = Tr[r * RP + 36 + j], S3i = Ti[r * RP + 36 + j];
      // twiddles: j<=11 so 2j,3j < 48 (no modulo)
      const float w1r = COS48[j],     w1i = -SIN48[j];
      const float w2r = COS48[2 * j], w2i = -SIN48[2 * j];
      const float w3r = COS48[3 * j], w3i = -SIN48[3 * j];
      const float T1r = S1r * w1r - S1i * w1i, T1i = S1r * w1i + S1i * w1r;
      const float T2r = S2r * w2r - S2i * w2i, T2i = S2r * w2i + S2i * w2r;
      const float T3r = S3r * w3r - S3i * w3i, T3i = S3r * w3i + S3i * w3r;
      // 4-pt DFT over b, kernel (-i)^{bc}
      const float er = S0r + T2r, ei = S0i + T2i;
      const float dr = S0r - T2r, di = S0i - T2i;
      const float fr = T1r + T3r, fi = T1i + T3i;
      const float gr = T1r - T3r, gi = T1i - T3i;
      const float s = (j & 1) ? -NORM : NORM;   // (-1)^f = (-1)^j since f = 12c+j
      const float c0r = (er + fr) * s, c0i = (ei + fi) * s;   // c=0
      const float c1r = (dr + gi) * s, c1i = (di - gr) * s;   // c=1: d - i g
      const float c2r = (er - fr) * s, c2i = (ei - fi) * s;   // c=2
      const float c3r = (dr - gi) * s, c3i = (di + gr) * s;   // c=3: d + i g
      og[j]      = bf16_rne(c0i) | (bf16_rne(c0r) << 16);
      og[12 + j] = bf16_rne(c1i) | (bf16_rne(c1r) << 16);
      og[24 + j] = bf16_rne(c2i) | (bf16_rne(c2r) << 16);
      og[36 + j] = bf16_rne(c3i) | (bf16_rne(c3r) << 16);
    }
  }
}

} // namespace

extern "C" void kernel_launch(void* const* d_in, const int* in_sizes, int n_in,
                              void* d_out, int out_size, void* d_ws, size_t ws_size,
                              hipStream_t stream) {
  const float* xr = (const float*)d_in[0];   // dict order: x_real first
  const float* xi = (const float*)d_in[1];
  unsigned* out = (unsigned*)d_out;          // dword = im(bf16) | re(bf16)<<16
  const int nbc = in_sizes[0] / 3072;        // 8192 blocks of (8*4*2*48)
  bd2af_kernel<<<nbc, 256, 0, stream>>>(xr, xi, out, nbc);
}